// Round 6
// baseline (171.935 us; speedup 1.0000x reference)
//
#include <hip/hip_runtime.h>
#include <math.h>

// Problem constants (fixed by the reference).
#define NITEMS 50000
#define BATCH  512
#define LLEN   50
#define KTOP   20
#define HDIM   32
#define DDIM   32
#define NCH    5
#define NSEG   33             // H+1 piecewise-linear segments
#define NSCAL  200            // scalars per item
#define NCELL  100            // (c,k) cells
#define NCELLH 50             // cells per half-block
#define THRP   33             // padded LDS stride for sorted thresholds
#define NWAVE  8              // waves per block
#define CSLOTH 7              // ceil(50/8) cells per 8-lane group

typedef _Float16 h2 __attribute__((ext_vector_type(2)));

static __device__ __forceinline__ float dot2_acc(h2 a, h2 b, float c) {
#if __has_builtin(__builtin_amdgcn_fdot2)
    return __builtin_amdgcn_fdot2(a, b, c, false);
#else
    return fmaf((float)a.x, (float)b.x, fmaf((float)a.y, (float)b.y, c));
#endif
}

// One cell's contribution: identical op order to the proven R11/R16 body.
static __device__ __forceinline__ float cellterm(uint2 xo, uint4 q0, uint4 q1,
        unsigned int wa, unsigned int wb, float a) {
    _Float16 x0h = __builtin_bit_cast(_Float16, (unsigned short)(xo.x & 0xffffu));
    _Float16 x1h = __builtin_bit_cast(_Float16, (unsigned short)(xo.y & 0xffffu));
    h2 x0 = {x0h, x0h}, x1 = {x1h, x1h};
    h2 repa = (x0 * __builtin_bit_cast(h2, q0.x) + __builtin_bit_cast(h2, q0.y))
            * (x1 * __builtin_bit_cast(h2, q1.x) + __builtin_bit_cast(h2, q1.y));
    h2 repb = (x0 * __builtin_bit_cast(h2, q0.z) + __builtin_bit_cast(h2, q0.w))
            * (x1 * __builtin_bit_cast(h2, q1.z) + __builtin_bit_cast(h2, q1.w));
    return dot2_acc(repa, __builtin_bit_cast(h2, wa),
           dot2_acc(repb, __builtin_bit_cast(h2, wb), a));
}

// ws layout (floats):
//   [0, 160)       sorted thr[c][0..31] (ascending per channel)
//   [160, 5440)    AB16 table: 5280 uints, fp16 swizzled (see below)
//   [5440, 5952)   row order (ints) from the length sort
#define WS_THRS  0
#define WS_AB16  160
#define WS_ORDER 5440

// fp16 table layout: row (c,s) = 32 uints (128 B).  Chunk d4 (0..7) = 4
// uints: [A(4d4,4d4+1), B(4d4,4d4+1), A(4d4+2,4d4+3), B(4d4+2,4d4+3)].

// ---------------------------------------------------------------------------
// R17 setup: slimmed 34 -> 2 blocks.  Block 0 computes the whole AB table
// with the R14-proven prefix/suffix scan (absmax 0.0 validated): each of the
// 160 (c,d) threads scans the 33 segments with running sums into pk[33]
// REGISTERS -- safe here because setup has no launch_bounds VGPR clamp (the
// R15 spill pathology was main's 64-VGPR envelope) -- then writes ws
// (global; no LDS read/write alias serialization).  Block 1: counting sort,
// verbatim.  Kills 33 redundant 20 KB W2 stagings.
// ---------------------------------------------------------------------------
__global__ __launch_bounds__(256) void cnn_setup(
        const float* __restrict__ W1, const float* __restrict__ b1,
        const float* __restrict__ W2, const float* __restrict__ b2,
        const int* __restrict__ user_lens,
        float* __restrict__ ws, int* __restrict__ order) {
    const int tid = threadIdx.x;

    if (blockIdx.x == 0) {
        __shared__ float sW1[NCH*HDIM], sB1[NCH*HDIM], sThr[NCH*HDIM];
        __shared__ int   sInv[NCH*HDIM];
        __shared__ float sW2[NCH*HDIM*DDIM];     // 20 KB
        __shared__ float sB2[NCH*DDIM];

        for (int i = tid; i < NCH*HDIM; i += 256) { sW1[i] = W1[i]; sB1[i] = b1[i]; }
        for (int i = tid; i < NCH*HDIM*DDIM; i += 256) sW2[i] = W2[i];
        for (int i = tid; i < NCH*DDIM; i += 256) sB2[i] = b2[i];
        __syncthreads();

        for (int i = tid; i < NCH*HDIM; i += 256) {
            float w = sW1[i];
            sThr[i] = (w != 0.f) ? (-sB1[i] / w) : INFINITY;
        }
        __syncthreads();

        for (int i = tid; i < NCH*HDIM; i += 256) {
            int c = i / HDIM, h = i % HDIM;
            float thr = sThr[i];
            int rank = 0;
            for (int h2i = 0; h2i < HDIM; ++h2i) {
                float thr2 = sThr[c*HDIM + h2i];
                rank += (thr2 < thr || (thr2 == thr && h2i < h)) ? 1 : 0;
            }
            sInv[c*HDIM + rank] = h;             // rank -> h (bijective per c)
            ws[WS_THRS + c*HDIM + rank] = thr;
        }
        __syncthreads();

        if (tid < NCH*DDIM) {
            const int c = tid >> 5, d = tid & 31;
            const int cb = c << 5;
            // Pass 1: negative-w suffix totals + zero-w class (h-order).
            float sa = 0.f, sb = 0.f, zb = 0.f;
#pragma unroll
            for (int h = 0; h < HDIM; ++h) {
                float wv = sW1[cb + h];
                float bb = sB1[cb + h];
                float w2 = sW2[((cb + h) << 5) + d];
                float aw = wv * w2, bw = bb * w2;
                if (wv < 0.f) { sa += aw; sb += bw; }
                else if (wv == 0.f && bb > 0.f) zb += bw;
            }
            const float b2v = sB2[cb + d] + zb;
            // Pass 2: rank-order scan into compile-time-indexed registers.
            unsigned int pk[NSEG];
            float pa = 0.f, pb = 0.f;
#pragma unroll
            for (int s = 0; s < NSEG; ++s) {
                _Float16 ah = (_Float16)(pa + sa);
                _Float16 bh = (_Float16)(pb + sb + b2v);
                pk[s] = (unsigned int)__builtin_bit_cast(unsigned short, ah)
                      | ((unsigned int)__builtin_bit_cast(unsigned short, bh) << 16);
                if (s < HDIM) {
                    int hh = sInv[cb + s];               // rank-s unit
                    float wv = sW1[cb + hh];
                    float bb = sB1[cb + hh];
                    float w2 = sW2[((cb + hh) << 5) + d];
                    float aw = wv * w2, bw = bb * w2;
                    if (wv > 0.f)      { pa += aw; pb += bw; }   // joins prefix
                    else if (wv < 0.f) { sa -= aw; sb -= bw; }   // leaves suffix
                }
            }
            // Pass 3: swizzled fp16 writes to global ws.
            unsigned short* ab = (unsigned short*)(ws + WS_AB16);
            const int dq = d >> 2, dd = d & 3;
            const int sub = 4*(dd>>1) + (dd&1);
#pragma unroll
            for (int s = 0; s < NSEG; ++s) {
                int base = ((c*NSEG + s)*32 + dq*4)*2;          // ushort index
                ab[base + sub]     = (unsigned short)(pk[s] & 0xffffu);
                ab[base + sub + 2] = (unsigned short)(pk[s] >> 16);
            }
        }
    } else {
        // ---- counting sort of rows by len (ascending) --------------------
        __shared__ int sHist[LLEN + 1];
        for (int i = tid; i <= LLEN; i += 256) sHist[i] = 0;
        __syncthreads();
        for (int i = tid; i < BATCH; i += 256) atomicAdd(&sHist[user_lens[i]], 1);
        __syncthreads();
        if (tid == 0) {
            int accum = 0;
            for (int l = 1; l <= LLEN; ++l) { int c = sHist[l]; sHist[l] = accum; accum += c; }
        }
        __syncthreads();
        for (int i = tid; i < BATCH; i += 256) {
            int pos = atomicAdd(&sHist[user_lens[i]], 1);
            order[pos] = i;
        }
    }
}

// ---------------------------------------------------------------------------
// R17 main = R16 half-row blocks (proven: 112.9us, absmax 0.0) with phase-C
// slots 4,5 offloaded to GLOBAL loads through L1.  Model: main is
// LDS-issue-bound (~290 cy/item-wave x ~102 item-waves/CU ~= 12.3us matches).
// Slots 4,5 (cells g+32, g+40: always < 50, no guard) move 4 of 14
// ds_read_b128 per item to global_load_dwordx4 on the vector-memory pipe;
// the 21KB table is L1/L2-resident and shared by all 4 blocks/CU.  Their
// sxo reads are hoisted first so the loads are in flight during LDS slots
// 0-3,6.  Everything else verbatim.  DO NOT restructure the stripe loop
// without checking WRITE_SIZE for spills (R7/R10/R15 pathology).
// ---------------------------------------------------------------------------
__global__ __launch_bounds__(512, 8) void cnn_main(
        const float* __restrict__ ctx,  const float* __restrict__ ws,
        const float* __restrict__ Wout, const float* __restrict__ bout,
        const int* __restrict__ item_idxs, const int* __restrict__ user_items,
        const int* __restrict__ user_lens, const int* __restrict__ order,
        float* __restrict__ out) {
    __shared__ unsigned int sAB16[NCH*NSEG*32];  // 21120 B, swizzled fp16
    __shared__ float  sThrS[NCH*THRP];           // sorted thr, stride 33
    __shared__ uint2  sxo[NWAVE][NCELLH];        // {x0h|off0<<16, x1h|off1<<16}
    __shared__ uint2  sWt[NCELLH*8];             // [cellL*8+d4] target wt bits
    __shared__ float  pRed[NWAVE][NCELLH];       // per-wave scalar partials

    const int tid  = threadIdx.x;
    const int w    = tid >> 6;              // wave 0..7
    const int lane = tid & 63;
    const int g    = lane >> 3;             // cell sub-group 0..7
    const int d4   = lane & 7;              // covers d = 4*d4 .. 4*d4+3

    const char* ABg = (const char*)(ws + WS_AB16);   // global table base (L1)

    // Stage fp16 table + sorted thresholds.
    const uint4* ABv = reinterpret_cast<const uint4*>(ws + WS_AB16);
    uint4* sAB4 = reinterpret_cast<uint4*>(sAB16);
    for (int i = tid; i < NCH*NSEG*8; i += 512) sAB4[i] = ABv[i];
    for (int i = tid; i < NCH*THRP; i += 512) {
        int c = i / THRP, j = i - c*THRP;
        sThrS[i] = (j < HDIM) ? ws[WS_THRS + c*HDIM + j] : 0.f;
    }

    // Block -> (row rank, cell half).  Sorted pairing preserved on rowSlot.
    const int rowSlot = blockIdx.x >> 1;
    const int half    = blockIdx.x & 1;     // k in [10*half, 10*half+10)
    const int rank = (rowSlot < 256) ? rowSlot : (767 - rowSlot);
    const int b    = order[rank];
    const int len  = user_lens[b];          // >= 1
    const float inv_len = 1.f / (float)len;
    const float bo = bout[0];
    const h2 wv0 = {(_Float16)Wout[4*d4],     (_Float16)Wout[4*d4 + 1]};
    const h2 wv1 = {(_Float16)Wout[4*d4 + 2], (_Float16)Wout[4*d4 + 3]};

    // Per-(lane,round) phase-S constants (fixed across items).
    int sc[2], sdst[2], sgi[2];
#pragma unroll
    for (int r = 0; r < 2; ++r) {
        int lidx = lane + 64*r;
        int c    = lidx / 20, rr = lidx - c*20;
        int slot = rr / 10,  kk = rr - slot*10;
        sc[r]   = (lidx < 100) ? c : 0;
        sdst[r] = (c*10 + kk)*8 + slot*4;   // byte offset in sxo[w]
        sgi[r]  = c*40 + slot*20 + half*10 + kk;
    }

    const int nstripe = (len > w) ? ((len - w + NWAVE - 1) / NWAVE) : 0;

    unsigned int wtA[CSLOTH], wtB[CSLOTH];  // target rep * Wout (h2 bits)
    float acc[CSLOTH];
#pragma unroll
    for (int i = 0; i < CSLOTH; ++i) acc[i] = 0.f;

    char* sxoB = (char*)&sxo[w][0];

    __syncthreads();                        // staging visible to all waves

    // Prefetch this wave's first stripe item (overlaps wave 0's target).
    float xp[2] = {0.f, 0.f};
    if (nstripe > 0) {
        const float* row = ctx + (size_t)user_items[b*LLEN + w] * NSCAL;
#pragma unroll
        for (int r = 0; r < 2; ++r) {
            int lidx = lane + 64*r;
            if (lidx < 100) xp[r] = row[sgi[r]];
        }
    }

    // ======== target item: wave 0 only, broadcast via sWt ================
    if (w == 0) {
        float xt[2] = {0.f, 0.f};
        const float* row = ctx + (size_t)item_idxs[b] * NSCAL;
#pragma unroll
        for (int r = 0; r < 2; ++r) {
            int lidx = lane + 64*r;
            if (lidx < 100) xt[r] = row[sgi[r]];
        }
#pragma unroll
        for (int r = 0; r < 2; ++r) {
            int lidx = lane + 64*r;
            if (lidx < 100) {
                float xv = xt[r];
                int base = sc[r]*THRP;
                int pos = 0;
                pos += (sThrS[base + pos + 15] < xv) ? 16 : 0;
                pos += (sThrS[base + pos + 7]  < xv) ? 8  : 0;
                pos += (sThrS[base + pos + 3]  < xv) ? 4  : 0;
                pos += (sThrS[base + pos + 1]  < xv) ? 2  : 0;
                pos += (sThrS[base + pos]      < xv) ? 1  : 0;
                unsigned int off = (unsigned int)((sc[r]*NSEG + pos) << 7);
                _Float16 xh = (_Float16)xv;
                unsigned int word = (unsigned int)__builtin_bit_cast(unsigned short, xh)
                                  | (off << 16);
                *(unsigned int*)(sxoB + sdst[r]) = word;
            }
        }
        __builtin_amdgcn_wave_barrier();
#pragma unroll
        for (int i = 0; i < CSLOTH; ++i) {
            int cell = g + 8*i;
            if (cell < NCELLH) {
                uint2 xo = sxo[0][cell];
                uint4 q0 = *(const uint4*)((const char*)sAB16 + (xo.x >> 16) + (d4 << 4));
                uint4 q1 = *(const uint4*)((const char*)sAB16 + (xo.y >> 16) + (d4 << 4));
                _Float16 x0h = __builtin_bit_cast(_Float16, (unsigned short)(xo.x & 0xffffu));
                _Float16 x1h = __builtin_bit_cast(_Float16, (unsigned short)(xo.y & 0xffffu));
                h2 x0 = {x0h, x0h}, x1 = {x1h, x1h};
                h2 repa = (x0 * __builtin_bit_cast(h2, q0.x) + __builtin_bit_cast(h2, q0.y))
                        * (x1 * __builtin_bit_cast(h2, q1.x) + __builtin_bit_cast(h2, q1.y));
                h2 repb = (x0 * __builtin_bit_cast(h2, q0.z) + __builtin_bit_cast(h2, q0.w))
                        * (x1 * __builtin_bit_cast(h2, q1.z) + __builtin_bit_cast(h2, q1.w));
                wtA[i] = __builtin_bit_cast(unsigned int, (h2)(repa * wv0));
                wtB[i] = __builtin_bit_cast(unsigned int, (h2)(repb * wv1));
                sWt[cell*8 + d4] = make_uint2(wtA[i], wtB[i]);
            }
        }
    }
    __syncthreads();                        // sWt ready for all waves

    if (w != 0) {
#pragma unroll
        for (int i = 0; i < CSLOTH; ++i) {
            int cell = g + 8*i;
            if (cell < NCELLH) {
                uint2 v = sWt[cell*8 + d4];
                wtA[i] = v.x; wtB[i] = v.y;
            }
        }
    }

    // ======== stripe items (this wave only; no per-item barriers) ========
    for (int j = 0; j < nstripe; ++j) {
        float xc[2];
#pragma unroll
        for (int r = 0; r < 2; ++r) xc[r] = xp[r];

        // prefetch next stripe item (latency hidden behind S+C)
        if (j + 1 < nstripe) {
            const float* row = ctx + (size_t)user_items[b*LLEN + w + NWAVE*(j+1)] * NSCAL;
#pragma unroll
            for (int r = 0; r < 2; ++r) {
                int lidx = lane + 64*r;
                if (lidx < 100) xp[r] = row[sgi[r]];
            }
        }

        // ---- phase S: binary-search segment, pack {fp16(x)|rowoff} ------
#pragma unroll
        for (int r = 0; r < 2; ++r) {
            int lidx = lane + 64*r;
            if (lidx < 100) {
                float xv = xc[r];
                int base = sc[r]*THRP;
                int pos = 0;
                pos += (sThrS[base + pos + 15] < xv) ? 16 : 0;
                pos += (sThrS[base + pos + 7]  < xv) ? 8  : 0;
                pos += (sThrS[base + pos + 3]  < xv) ? 4  : 0;
                pos += (sThrS[base + pos + 1]  < xv) ? 2  : 0;
                pos += (sThrS[base + pos]      < xv) ? 1  : 0;
                unsigned int off = (unsigned int)((sc[r]*NSEG + pos) << 7);
                _Float16 xh = (_Float16)xv;
                unsigned int word = (unsigned int)__builtin_bit_cast(unsigned short, xh)
                                  | (off << 16);
                *(unsigned int*)(sxoB + sdst[r]) = word;
            }
        }
        __builtin_amdgcn_wave_barrier();

        // ---- phase C: slots 4,5 from GLOBAL (L1), rest from LDS ----------
        uint2 xo4 = sxo[w][g + 32];          // cells g+32, g+40: always < 50
        uint2 xo5 = sxo[w][g + 40];
        uint4 q40 = *(const uint4*)(ABg + (xo4.x >> 16) + (d4 << 4));
        uint4 q41 = *(const uint4*)(ABg + (xo4.y >> 16) + (d4 << 4));
        uint4 q50 = *(const uint4*)(ABg + (xo5.x >> 16) + (d4 << 4));
        uint4 q51 = *(const uint4*)(ABg + (xo5.y >> 16) + (d4 << 4));
#pragma unroll
        for (int i = 0; i < CSLOTH; ++i) {
            if (i == 4 || i == 5) continue;
            int cell = g + 8*i;
            if (cell < NCELLH) {
                uint2 xo = sxo[w][cell];
                uint4 q0 = *(const uint4*)((const char*)sAB16 + (xo.x >> 16) + (d4 << 4));
                uint4 q1 = *(const uint4*)((const char*)sAB16 + (xo.y >> 16) + (d4 << 4));
                acc[i] = cellterm(xo, q0, q1, wtA[i], wtB[i], acc[i]);
            }
        }
        acc[4] = cellterm(xo4, q40, q41, wtA[4], wtB[4], acc[4]);
        acc[5] = cellterm(xo5, q50, q51, wtA[5], wtB[5], acc[5]);
        __builtin_amdgcn_wave_barrier();
    }

    // ---- epilogue: 8-lane reduce, cross-wave combine, sigmoid -----------
#pragma unroll
    for (int i = 0; i < CSLOTH; ++i) {
        int cell = g + 8*i;
        float v = acc[i];
        v += __shfl_xor(v, 1, 64);
        v += __shfl_xor(v, 2, 64);
        v += __shfl_xor(v, 4, 64);
        if (d4 == 0 && cell < NCELLH) pRed[w][cell] = v;
    }
    __syncthreads();
    if (tid < NCELLH) {
        float p = 0.f;
#pragma unroll
        for (int q = 0; q < NWAVE; ++q) p += pRed[q][tid];
        int cellG = (tid / 10)*KTOP + half*10 + (tid % 10);
        out[b*NCELL + cellG] = 1.f / (1.f + expf(-(p*inv_len + bo)));
    }
}

extern "C" void kernel_launch(void* const* d_in, const int* in_sizes, int n_in,
                              void* d_out, int out_size, void* d_ws, size_t ws_size,
                              hipStream_t stream) {
    const float* ctx   = (const float*)d_in[0];
    const float* W1    = (const float*)d_in[1];
    const float* b1    = (const float*)d_in[2];
    const float* W2    = (const float*)d_in[3];
    const float* b2    = (const float*)d_in[4];
    const float* Wout  = (const float*)d_in[5];
    const float* bout  = (const float*)d_in[6];
    const int* item_idxs  = (const int*)d_in[7];
    const int* user_items = (const int*)d_in[8];
    const int* user_lens  = (const int*)d_in[9];
    float* out = (float*)d_out;
    float* ws  = (float*)d_ws;                 // uses 23,808 B
    int*   order = (int*)(ws + WS_ORDER);

    cnn_setup<<<2, 256, 0, stream>>>(W1, b1, W2, b2, user_lens, ws, order);
    cnn_main<<<2*BATCH, 512, 0, stream>>>(ctx, ws, Wout, bout,
                                          item_idxs, user_items, user_lens,
                                          order, out);
}

// Round 7
// 112.691 us; speedup vs baseline: 1.5257x; 1.5257x over previous
//
#include <hip/hip_runtime.h>
#include <math.h>

// Problem constants (fixed by the reference).
#define NITEMS 50000
#define BATCH  512
#define LLEN   50
#define KTOP   20
#define HDIM   32
#define DDIM   32
#define NCH    5
#define NSEG   33             // H+1 piecewise-linear segments
#define NSCAL  200            // scalars per item
#define NCELL  100            // (c,k) cells
#define NCELLH 50             // cells per half-block
#define THRP   33             // padded LDS stride for sorted thresholds
#define NWAVE  8              // waves per block
#define CSLOTH 7              // ceil(50/8) cells per 8-lane group

typedef _Float16 h2 __attribute__((ext_vector_type(2)));

static __device__ __forceinline__ float dot2_acc(h2 a, h2 b, float c) {
#if __has_builtin(__builtin_amdgcn_fdot2)
    return __builtin_amdgcn_fdot2(a, b, c, false);
#else
    return fmaf((float)a.x, (float)b.x, fmaf((float)a.y, (float)b.y, c));
#endif
}

// ws layout (floats):
//   [0, 160)       sorted thr[c][0..31] (ascending per channel)
//   [160, 5440)    AB16 table: 5280 uints, fp16 swizzled (see below)
//   [5440, 5952)   row order (ints) from the length sort
#define WS_THRS  0
#define WS_AB16  160
#define WS_ORDER 5440

// fp16 table layout: row (c,s) = 32 uints (128 B).  Chunk d4 (0..7) = 4
// uints: [A(4d4,4d4+1), B(4d4,4d4+1), A(4d4+2,4d4+3), B(4d4+2,4d4+3)].

// ---------------------------------------------------------------------------
// R18 = R16 main (proven 112.9us) + R17 slim setup (numerically validated).
// R17 post-mortem: the phase-C global-offload's 4 in-flight uint4 loads
// (16 VGPR + addresses) broke the 64-VGPR envelope -> allocator collapsed to
// VGPR 32 with 160 MB scratch WRITE_SIZE (4th spill occurrence).  HARD RULE:
// the stripe loop has ZERO register headroom -- no new live state, however
// small.  Setup slim is exonerated (absmax 0.0; not in top-5).
// ---------------------------------------------------------------------------
__global__ __launch_bounds__(256) void cnn_setup(
        const float* __restrict__ W1, const float* __restrict__ b1,
        const float* __restrict__ W2, const float* __restrict__ b2,
        const int* __restrict__ user_lens,
        float* __restrict__ ws, int* __restrict__ order) {
    const int tid = threadIdx.x;

    if (blockIdx.x == 0) {
        __shared__ float sW1[NCH*HDIM], sB1[NCH*HDIM], sThr[NCH*HDIM];
        __shared__ int   sInv[NCH*HDIM];
        __shared__ float sW2[NCH*HDIM*DDIM];     // 20 KB
        __shared__ float sB2[NCH*DDIM];

        for (int i = tid; i < NCH*HDIM; i += 256) { sW1[i] = W1[i]; sB1[i] = b1[i]; }
        for (int i = tid; i < NCH*HDIM*DDIM; i += 256) sW2[i] = W2[i];
        for (int i = tid; i < NCH*DDIM; i += 256) sB2[i] = b2[i];
        __syncthreads();

        for (int i = tid; i < NCH*HDIM; i += 256) {
            float w = sW1[i];
            sThr[i] = (w != 0.f) ? (-sB1[i] / w) : INFINITY;
        }
        __syncthreads();

        for (int i = tid; i < NCH*HDIM; i += 256) {
            int c = i / HDIM, h = i % HDIM;
            float thr = sThr[i];
            int rank = 0;
            for (int h2i = 0; h2i < HDIM; ++h2i) {
                float thr2 = sThr[c*HDIM + h2i];
                rank += (thr2 < thr || (thr2 == thr && h2i < h)) ? 1 : 0;
            }
            sInv[c*HDIM + rank] = h;             // rank -> h (bijective per c)
            ws[WS_THRS + c*HDIM + rank] = thr;
        }
        __syncthreads();

        if (tid < NCH*DDIM) {
            const int c = tid >> 5, d = tid & 31;
            const int cb = c << 5;
            // Pass 1: negative-w suffix totals + zero-w class (h-order).
            float sa = 0.f, sb = 0.f, zb = 0.f;
#pragma unroll
            for (int h = 0; h < HDIM; ++h) {
                float wv = sW1[cb + h];
                float bb = sB1[cb + h];
                float w2 = sW2[((cb + h) << 5) + d];
                float aw = wv * w2, bw = bb * w2;
                if (wv < 0.f) { sa += aw; sb += bw; }
                else if (wv == 0.f && bb > 0.f) zb += bw;
            }
            const float b2v = sB2[cb + d] + zb;
            // Pass 2: rank-order scan into compile-time-indexed registers.
            unsigned int pk[NSEG];
            float pa = 0.f, pb = 0.f;
#pragma unroll
            for (int s = 0; s < NSEG; ++s) {
                _Float16 ah = (_Float16)(pa + sa);
                _Float16 bh = (_Float16)(pb + sb + b2v);
                pk[s] = (unsigned int)__builtin_bit_cast(unsigned short, ah)
                      | ((unsigned int)__builtin_bit_cast(unsigned short, bh) << 16);
                if (s < HDIM) {
                    int hh = sInv[cb + s];               // rank-s unit
                    float wv = sW1[cb + hh];
                    float bb = sB1[cb + hh];
                    float w2 = sW2[((cb + hh) << 5) + d];
                    float aw = wv * w2, bw = bb * w2;
                    if (wv > 0.f)      { pa += aw; pb += bw; }   // joins prefix
                    else if (wv < 0.f) { sa -= aw; sb -= bw; }   // leaves suffix
                }
            }
            // Pass 3: swizzled fp16 writes to global ws.
            unsigned short* ab = (unsigned short*)(ws + WS_AB16);
            const int dq = d >> 2, dd = d & 3;
            const int sub = 4*(dd>>1) + (dd&1);
#pragma unroll
            for (int s = 0; s < NSEG; ++s) {
                int base = ((c*NSEG + s)*32 + dq*4)*2;          // ushort index
                ab[base + sub]     = (unsigned short)(pk[s] & 0xffffu);
                ab[base + sub + 2] = (unsigned short)(pk[s] >> 16);
            }
        }
    } else {
        // ---- counting sort of rows by len (ascending) --------------------
        __shared__ int sHist[LLEN + 1];
        for (int i = tid; i <= LLEN; i += 256) sHist[i] = 0;
        __syncthreads();
        for (int i = tid; i < BATCH; i += 256) atomicAdd(&sHist[user_lens[i]], 1);
        __syncthreads();
        if (tid == 0) {
            int accum = 0;
            for (int l = 1; l <= LLEN; ++l) { int c = sHist[l]; sHist[l] = accum; accum += c; }
        }
        __syncthreads();
        for (int i = tid; i < BATCH; i += 256) {
            int pos = atomicAdd(&sHist[user_lens[i]], 1);
            order[pos] = i;
        }
    }
}

// ---------------------------------------------------------------------------
// R18 main: R16 half-row blocks, VERBATIM (proven: 112.9us, absmax 0.0).
// Cell (c,k) needs only scalars c*40+k and c*40+20+k, so the k-dimension
// splits cleanly: block = (row, half), half h owns k in [10h, 10h+10) ->
// 100 scalars, 50 cells, own 50 outputs, NO cross-block reduction.  Grid
// 1024 (4 blocks/CU); per-item serial work halved vs full-row (phase S 2
// rounds, phase C 7 slots); LDS 29.8 KB.  DO NOT restructure the stripe
// loop and DO NOT add live registers to it (R7/R10/R15/R17 spill
// pathology -- check WRITE_SIZE after ANY change here).
// ---------------------------------------------------------------------------
__global__ __launch_bounds__(512, 8) void cnn_main(
        const float* __restrict__ ctx,  const float* __restrict__ ws,
        const float* __restrict__ Wout, const float* __restrict__ bout,
        const int* __restrict__ item_idxs, const int* __restrict__ user_items,
        const int* __restrict__ user_lens, const int* __restrict__ order,
        float* __restrict__ out) {
    __shared__ unsigned int sAB16[NCH*NSEG*32];  // 21120 B, swizzled fp16
    __shared__ float  sThrS[NCH*THRP];           // sorted thr, stride 33
    __shared__ uint2  sxo[NWAVE][NCELLH];        // {x0h|off0<<16, x1h|off1<<16}
    __shared__ uint2  sWt[NCELLH*8];             // [cellL*8+d4] target wt bits
    __shared__ float  pRed[NWAVE][NCELLH];       // per-wave scalar partials

    const int tid  = threadIdx.x;
    const int w    = tid >> 6;              // wave 0..7
    const int lane = tid & 63;
    const int g    = lane >> 3;             // cell sub-group 0..7
    const int d4   = lane & 7;              // covers d = 4*d4 .. 4*d4+3

    // Stage fp16 table + sorted thresholds.
    const uint4* ABg = reinterpret_cast<const uint4*>(ws + WS_AB16);
    uint4* sAB4 = reinterpret_cast<uint4*>(sAB16);
    for (int i = tid; i < NCH*NSEG*8; i += 512) sAB4[i] = ABg[i];
    for (int i = tid; i < NCH*THRP; i += 512) {
        int c = i / THRP, j = i - c*THRP;
        sThrS[i] = (j < HDIM) ? ws[WS_THRS + c*HDIM + j] : 0.f;
    }

    // Block -> (row rank, cell half).  Sorted pairing preserved on rowSlot.
    const int rowSlot = blockIdx.x >> 1;
    const int half    = blockIdx.x & 1;     // k in [10*half, 10*half+10)
    const int rank = (rowSlot < 256) ? rowSlot : (767 - rowSlot);
    const int b    = order[rank];
    const int len  = user_lens[b];          // >= 1
    const float inv_len = 1.f / (float)len;
    const float bo = bout[0];
    const h2 wv0 = {(_Float16)Wout[4*d4],     (_Float16)Wout[4*d4 + 1]};
    const h2 wv1 = {(_Float16)Wout[4*d4 + 2], (_Float16)Wout[4*d4 + 3]};

    // Per-(lane,round) phase-S constants (fixed across items).
    // Local enumeration lidx in [0,100): c = lidx/20, rr = lidx%20,
    // slot = rr/10, kk = rr%10.  Local cell = c*10+kk; row scalar index
    // = c*40 + slot*20 + half*10 + kk.
    int sc[2], sdst[2], sgi[2];
#pragma unroll
    for (int r = 0; r < 2; ++r) {
        int lidx = lane + 64*r;
        int c    = lidx / 20, rr = lidx - c*20;
        int slot = rr / 10,  kk = rr - slot*10;
        sc[r]   = (lidx < 100) ? c : 0;
        sdst[r] = (c*10 + kk)*8 + slot*4;   // byte offset in sxo[w]
        sgi[r]  = c*40 + slot*20 + half*10 + kk;
    }

    const int nstripe = (len > w) ? ((len - w + NWAVE - 1) / NWAVE) : 0;

    unsigned int wtA[CSLOTH], wtB[CSLOTH];  // target rep * Wout (h2 bits)
    float acc[CSLOTH];
#pragma unroll
    for (int i = 0; i < CSLOTH; ++i) acc[i] = 0.f;

    char* sxoB = (char*)&sxo[w][0];

    __syncthreads();                        // staging visible to all waves

    // Prefetch this wave's first stripe item (overlaps wave 0's target).
    float xp[2] = {0.f, 0.f};
    if (nstripe > 0) {
        const float* row = ctx + (size_t)user_items[b*LLEN + w] * NSCAL;
#pragma unroll
        for (int r = 0; r < 2; ++r) {
            int lidx = lane + 64*r;
            if (lidx < 100) xp[r] = row[sgi[r]];
        }
    }

    // ======== target item: wave 0 only, broadcast via sWt ================
    if (w == 0) {
        float xt[2] = {0.f, 0.f};
        const float* row = ctx + (size_t)item_idxs[b] * NSCAL;
#pragma unroll
        for (int r = 0; r < 2; ++r) {
            int lidx = lane + 64*r;
            if (lidx < 100) xt[r] = row[sgi[r]];
        }
#pragma unroll
        for (int r = 0; r < 2; ++r) {
            int lidx = lane + 64*r;
            if (lidx < 100) {
                float xv = xt[r];
                int base = sc[r]*THRP;
                int pos = 0;
                pos += (sThrS[base + pos + 15] < xv) ? 16 : 0;
                pos += (sThrS[base + pos + 7]  < xv) ? 8  : 0;
                pos += (sThrS[base + pos + 3]  < xv) ? 4  : 0;
                pos += (sThrS[base + pos + 1]  < xv) ? 2  : 0;
                pos += (sThrS[base + pos]      < xv) ? 1  : 0;
                unsigned int off = (unsigned int)((sc[r]*NSEG + pos) << 7);
                _Float16 xh = (_Float16)xv;
                unsigned int word = (unsigned int)__builtin_bit_cast(unsigned short, xh)
                                  | (off << 16);
                *(unsigned int*)(sxoB + sdst[r]) = word;
            }
        }
        __builtin_amdgcn_wave_barrier();
#pragma unroll
        for (int i = 0; i < CSLOTH; ++i) {
            int cell = g + 8*i;
            if (cell < NCELLH) {
                uint2 xo = sxo[0][cell];
                const uint4* p0 = (const uint4*)((const char*)sAB16 + (xo.x >> 16) + (d4 << 4));
                const uint4* p1 = (const uint4*)((const char*)sAB16 + (xo.y >> 16) + (d4 << 4));
                uint4 q0 = *p0, q1 = *p1;
                _Float16 x0h = __builtin_bit_cast(_Float16, (unsigned short)(xo.x & 0xffffu));
                _Float16 x1h = __builtin_bit_cast(_Float16, (unsigned short)(xo.y & 0xffffu));
                h2 x0 = {x0h, x0h}, x1 = {x1h, x1h};
                h2 repa = (x0 * __builtin_bit_cast(h2, q0.x) + __builtin_bit_cast(h2, q0.y))
                        * (x1 * __builtin_bit_cast(h2, q1.x) + __builtin_bit_cast(h2, q1.y));
                h2 repb = (x0 * __builtin_bit_cast(h2, q0.z) + __builtin_bit_cast(h2, q0.w))
                        * (x1 * __builtin_bit_cast(h2, q1.z) + __builtin_bit_cast(h2, q1.w));
                wtA[i] = __builtin_bit_cast(unsigned int, (h2)(repa * wv0));
                wtB[i] = __builtin_bit_cast(unsigned int, (h2)(repb * wv1));
                sWt[cell*8 + d4] = make_uint2(wtA[i], wtB[i]);
            }
        }
    }
    __syncthreads();                        // sWt ready for all waves

    if (w != 0) {
#pragma unroll
        for (int i = 0; i < CSLOTH; ++i) {
            int cell = g + 8*i;
            if (cell < NCELLH) {
                uint2 v = sWt[cell*8 + d4];
                wtA[i] = v.x; wtB[i] = v.y;
            }
        }
    }

    // ======== stripe items (this wave only; no per-item barriers) ========
    for (int j = 0; j < nstripe; ++j) {
        float xc[2];
#pragma unroll
        for (int r = 0; r < 2; ++r) xc[r] = xp[r];

        // prefetch next stripe item (latency hidden behind S+C)
        if (j + 1 < nstripe) {
            const float* row = ctx + (size_t)user_items[b*LLEN + w + NWAVE*(j+1)] * NSCAL;
#pragma unroll
            for (int r = 0; r < 2; ++r) {
                int lidx = lane + 64*r;
                if (lidx < 100) xp[r] = row[sgi[r]];
            }
        }

        // ---- phase S: binary-search segment, pack {fp16(x)|rowoff} ------
#pragma unroll
        for (int r = 0; r < 2; ++r) {
            int lidx = lane + 64*r;
            if (lidx < 100) {
                float xv = xc[r];
                int base = sc[r]*THRP;
                int pos = 0;
                pos += (sThrS[base + pos + 15] < xv) ? 16 : 0;
                pos += (sThrS[base + pos + 7]  < xv) ? 8  : 0;
                pos += (sThrS[base + pos + 3]  < xv) ? 4  : 0;
                pos += (sThrS[base + pos + 1]  < xv) ? 2  : 0;
                pos += (sThrS[base + pos]      < xv) ? 1  : 0;
                unsigned int off = (unsigned int)((sc[r]*NSEG + pos) << 7);
                _Float16 xh = (_Float16)xv;
                unsigned int word = (unsigned int)__builtin_bit_cast(unsigned short, xh)
                                  | (off << 16);
                *(unsigned int*)(sxoB + sdst[r]) = word;
            }
        }
        __builtin_amdgcn_wave_barrier();

        // ---- phase C: 50 cells x 32 d by this wave alone -----------------
#pragma unroll
        for (int i = 0; i < CSLOTH; ++i) {
            int cell = g + 8*i;
            if (cell < NCELLH) {
                uint2 xo = sxo[w][cell];
                const uint4* p0 = (const uint4*)((const char*)sAB16 + (xo.x >> 16) + (d4 << 4));
                const uint4* p1 = (const uint4*)((const char*)sAB16 + (xo.y >> 16) + (d4 << 4));
                uint4 q0 = *p0, q1 = *p1;
                _Float16 x0h = __builtin_bit_cast(_Float16, (unsigned short)(xo.x & 0xffffu));
                _Float16 x1h = __builtin_bit_cast(_Float16, (unsigned short)(xo.y & 0xffffu));
                h2 x0 = {x0h, x0h}, x1 = {x1h, x1h};
                h2 repa = (x0 * __builtin_bit_cast(h2, q0.x) + __builtin_bit_cast(h2, q0.y))
                        * (x1 * __builtin_bit_cast(h2, q1.x) + __builtin_bit_cast(h2, q1.y));
                h2 repb = (x0 * __builtin_bit_cast(h2, q0.z) + __builtin_bit_cast(h2, q0.w))
                        * (x1 * __builtin_bit_cast(h2, q1.z) + __builtin_bit_cast(h2, q1.w));
                acc[i] = dot2_acc(repa, __builtin_bit_cast(h2, wtA[i]),
                         dot2_acc(repb, __builtin_bit_cast(h2, wtB[i]), acc[i]));
            }
        }
        __builtin_amdgcn_wave_barrier();
    }

    // ---- epilogue: 8-lane reduce, cross-wave combine, sigmoid -----------
#pragma unroll
    for (int i = 0; i < CSLOTH; ++i) {
        int cell = g + 8*i;
        float v = acc[i];
        v += __shfl_xor(v, 1, 64);
        v += __shfl_xor(v, 2, 64);
        v += __shfl_xor(v, 4, 64);
        if (d4 == 0 && cell < NCELLH) pRed[w][cell] = v;
    }
    __syncthreads();
    if (tid < NCELLH) {
        float p = 0.f;
#pragma unroll
        for (int q = 0; q < NWAVE; ++q) p += pRed[q][tid];
        int cellG = (tid / 10)*KTOP + half*10 + (tid % 10);
        out[b*NCELL + cellG] = 1.f / (1.f + expf(-(p*inv_len + bo)));
    }
}

extern "C" void kernel_launch(void* const* d_in, const int* in_sizes, int n_in,
                              void* d_out, int out_size, void* d_ws, size_t ws_size,
                              hipStream_t stream) {
    const float* ctx   = (const float*)d_in[0];
    const float* W1    = (const float*)d_in[1];
    const float* b1    = (const float*)d_in[2];
    const float* W2    = (const float*)d_in[3];
    const float* b2    = (const float*)d_in[4];
    const float* Wout  = (const float*)d_in[5];
    const float* bout  = (const float*)d_in[6];
    const int* item_idxs  = (const int*)d_in[7];
    const int* user_items = (const int*)d_in[8];
    const int* user_lens  = (const int*)d_in[9];
    float* out = (float*)d_out;
    float* ws  = (float*)d_ws;                 // uses 23,808 B
    int*   order = (int*)(ws + WS_ORDER);

    cnn_setup<<<2, 256, 0, stream>>>(W1, b1, W2, b2, user_lens, ws, order);
    cnn_main<<<2*BATCH, 512, 0, stream>>>(ctx, ws, Wout, bout,
                                          item_idxs, user_items, user_lens,
                                          order, out);
}